// Round 6
// baseline (470.747 us; speedup 1.0000x reference)
//
#include <hip/hip_runtime.h>

#define N_NODES 50000
#define N_EDGES 1600000

typedef __attribute__((ext_vector_type(4))) float f32x4;
typedef __attribute__((ext_vector_type(8))) short bf16x8;
typedef unsigned short u16;

__device__ __forceinline__ float lrelu(float x) { return x >= 0.f ? x : 0.01f * x; }

__device__ __forceinline__ u16 f2bf(float f) {
    union { float f; unsigned u; } v; v.f = f;
    unsigned u = v.u;
    u += 0x7fffu + ((u >> 16) & 1u);
    return (u16)(u >> 16);
}

__device__ __forceinline__ float bf2f(u16 v) {
    union { unsigned u; float f; } x; x.u = ((unsigned)v) << 16; return x.f;
}

__device__ __forceinline__ bf16x8 cvt8(float4 a, float4 b) {
    bf16x8 r;
    r[0] = (short)f2bf(a.x); r[1] = (short)f2bf(a.y);
    r[2] = (short)f2bf(a.z); r[3] = (short)f2bf(a.w);
    r[4] = (short)f2bf(b.x); r[5] = (short)f2bf(b.y);
    r[6] = (short)f2bf(b.z); r[7] = (short)f2bf(b.w);
    return r;
}

__device__ __forceinline__ void gload_lds16(const void* g, void* l) {
    __builtin_amdgcn_global_load_lds(
        (const __attribute__((address_space(1))) void*)g,
        (__attribute__((address_space(3))) void*)l, 16, 0, 0);
}

// ---------------------------------------------------------------------------
// k_wprep (merged): fragment-ordered bf16 tables Wf[kstep][nf][lane][8]
// element (ks,nf,lane,e) = W[nf*16 + (lane&15)][ks*32 + 8*(lane>>4) + e]
// blocks [0,1024): wf1 from lin1_w; [1024,1088): wf2; [1088,1104): wf3
// ---------------------------------------------------------------------------
__launch_bounds__(256)
__global__ void k_wprep(const float* __restrict__ W1,
                        const float* __restrict__ W2a, const float* __restrict__ W2b,
                        const float* __restrict__ W3a, const float* __restrict__ W3b,
                        u16* __restrict__ wf1, u16* __restrict__ wf2, u16* __restrict__ wf3)
{
    const int b = blockIdx.x;
    if (b < 1024) {
        int i = b * 256 + threadIdx.x;
        int e = i & 7, lane = (i >> 3) & 63, nf = (i >> 9) & 7, ks = i >> 12;
        int n = nf * 16 + (lane & 15);
        int k = ks * 32 + 8 * (lane >> 4) + e;
        wf1[i] = f2bf(W1[(size_t)n * 2048 + k]);
    } else if (b < 1088) {
        int i = (b - 1024) * 256 + threadIdx.x;
        int e = i & 7, lane = (i >> 3) & 63, nf = (i >> 9) & 7, ks = i >> 12;
        int n = nf * 16 + (lane & 15);
        int k = ks * 32 + 8 * (lane >> 4) + e;
        float v = (n < 64) ? W2a[(size_t)n * 128 + k] : W2b[(size_t)(n - 64) * 128 + k];
        wf2[i] = f2bf(v);
    } else {
        int i = (b - 1088) * 256 + threadIdx.x;
        int e = i & 7, lane = (i >> 3) & 63, nf = (i >> 9) & 3, ks = i >> 11;
        int n = nf * 16 + (lane & 15);
        int k = ks * 32 + 8 * (lane >> 4) + e;
        float v = (n < 32) ? W3a[(size_t)n * 64 + k] : W3b[(size_t)(n - 32) * 64 + k];
        wf3[i] = f2bf(v);
    }
}

// ---------------------------------------------------------------------------
// k_lin1p: h1(bf16) = lrelu(x @ lin1_w.T + b)
// 4-slot LDS ring, counted vmcnt (T3+T4): never drains to 0 in the loop.
// Slot = A[64 rows][32 k f32, 16B-granule XOR swz] 8KB + B[8KB wf1 slice].
// Per stage: 4 gload_lds16/thread (A0,A1,B0,B1 in FIFO order).
// Step s: wait vmcnt(12) [stage s done] -> bar -> MFMA(slot s%4) -> bar
//         -> issue stage s+4 into slot s%4 (all waves past compute).
// ---------------------------------------------------------------------------
__device__ __forceinline__ void stage_step(const float* __restrict__ X,
                                           const u16* __restrict__ Wf,
                                           char* slot, int m0, int s, int t)
{
    const int wave = t >> 6, l = t & 63;
    const int j = l >> 3, g = l & 7;
#pragma unroll
    for (int r = 0; r < 2; r++) {
        int lrow = r * 32 + wave * 8 + j;
        int grow = m0 + lrow; if (grow >= N_NODES) grow = N_NODES - 1;
        const float* srcA = X + (size_t)grow * 2048 + s * 32 + (((g ^ j) * 16) >> 2);
        gload_lds16(srcA, slot + r * 4096 + wave * 1024);
    }
#pragma unroll
    for (int r = 0; r < 2; r++) {
        const u16* srcB = Wf + (size_t)s * 4096 + (size_t)(r * 256 + t) * 8;
        gload_lds16(srcB, slot + 8192 + r * 4096 + wave * 1024);
    }
}

__device__ __forceinline__ void compute_step(const char* slot, int lane, int wave,
                                             f32x4 acc[8])
{
    const int lrow = lane & 15, lgrp = lane >> 4;
    const int row = wave * 16 + lrow;
    const int swz = (row & 7) << 4;
    const char* Ab = slot + row * 128;
    float4 a0 = *(const float4*)(Ab + ((lgrp * 32) ^ swz));
    float4 a1 = *(const float4*)(Ab + ((lgrp * 32 + 16) ^ swz));
    bf16x8 af = cvt8(a0, a1);
    const char* Bb = slot + 8192 + lane * 16;
#pragma unroll
    for (int nf = 0; nf < 8; nf++) {
        bf16x8 bf = *(const bf16x8*)(Bb + nf * 1024);
        acc[nf] = __builtin_amdgcn_mfma_f32_16x16x32_bf16(af, bf, acc[nf], 0, 0, 0);
    }
}

__launch_bounds__(256, 2)
__global__ void k_lin1p(const float* __restrict__ X, const u16* __restrict__ Wf,
                        const float* __restrict__ Bv, u16* __restrict__ H)
{
    __shared__ __align__(16) char lds[4][16384];
    const int t = threadIdx.x, wave = t >> 6, lane = t & 63;
    const int lrow = lane & 15, lgrp = lane >> 4;
    const int m0 = blockIdx.x * 64;

    f32x4 acc[8];
#pragma unroll
    for (int i = 0; i < 8; i++) acc[i] = (f32x4)0.f;

#pragma unroll
    for (int s = 0; s < 4; s++) stage_step(X, Wf, lds[s], m0, s, t);

    for (int s = 0; s < 60; s++) {
        asm volatile("s_waitcnt vmcnt(12)" ::: "memory");
        __builtin_amdgcn_s_barrier();
        compute_step(lds[s & 3], lane, wave, acc);
        __builtin_amdgcn_s_barrier();
        stage_step(X, Wf, lds[s & 3], m0, s + 4, t);
    }
    // peeled tail: stages 60..63 already issued, drain progressively
    asm volatile("s_waitcnt vmcnt(12)" ::: "memory");
    __builtin_amdgcn_s_barrier();
    compute_step(lds[0], lane, wave, acc);
    __builtin_amdgcn_s_barrier();
    asm volatile("s_waitcnt vmcnt(8)" ::: "memory");
    __builtin_amdgcn_s_barrier();
    compute_step(lds[1], lane, wave, acc);
    __builtin_amdgcn_s_barrier();
    asm volatile("s_waitcnt vmcnt(4)" ::: "memory");
    __builtin_amdgcn_s_barrier();
    compute_step(lds[2], lane, wave, acc);
    __builtin_amdgcn_s_barrier();
    asm volatile("s_waitcnt vmcnt(0)" ::: "memory");
    __builtin_amdgcn_s_barrier();
    compute_step(lds[3], lane, wave, acc);

    const int rbase = m0 + wave * 16 + lgrp * 4;
#pragma unroll
    for (int nf = 0; nf < 8; nf++) {
        const int col = nf * 16 + lrow;
        const float bias = Bv[col];
#pragma unroll
        for (int r = 0; r < 4; r++) {
            const int row = rbase + r;
            if (row < N_NODES)
                H[(size_t)row * 128 + col] = f2bf(lrelu(acc[nf][r] + bias));
        }
    }
}

// ---------------------------------------------------------------------------
// k_dualf1: t1(bf16, split halves) = h1 @ c1_wrel.T ; acc1 = h1 @ c1_wroot.T + b
// ---------------------------------------------------------------------------
__launch_bounds__(256, 2)
__global__ void k_dualf1(const u16* __restrict__ Hb, const u16* __restrict__ Wf,
                         const float* __restrict__ brel,
                         u16* __restrict__ t1h, float* __restrict__ acc1)
{
    const int t = threadIdx.x, wave = t >> 6, lane = t & 63;
    const int lrow = lane & 15, lgrp = lane >> 4;
    const int arow = blockIdx.x * 64 + wave * 16 + lrow;
    const u16* ap = Hb + (size_t)(arow < N_NODES ? arow : 0) * 128 + 8 * lgrp;
    const u16* bp = Wf + lane * 8;

    f32x4 acc[8];
#pragma unroll
    for (int i = 0; i < 8; i++) acc[i] = (f32x4)0.f;

    bf16x8 a0 = *(const bf16x8*)(ap + 0);
    bf16x8 a1 = *(const bf16x8*)(ap + 32);
    bf16x8 a2 = *(const bf16x8*)(ap + 64);
    bf16x8 a3 = *(const bf16x8*)(ap + 96);
    bf16x8 af[4] = {a0, a1, a2, a3};

#pragma unroll
    for (int ks = 0; ks < 4; ks++) {
        const u16* b = bp + ks * 4096;
        bf16x8 a = af[ks];
#pragma unroll
        for (int nf = 0; nf < 8; nf++) {
            bf16x8 bf = *(const bf16x8*)(b + nf * 512);
            acc[nf] = __builtin_amdgcn_mfma_f32_16x16x32_bf16(a, bf, acc[nf], 0, 0, 0);
        }
    }

    const int rbase = blockIdx.x * 64 + wave * 16 + lgrp * 4;
#pragma unroll
    for (int nf = 0; nf < 8; nf++) {
        const int col = nf * 16 + lrow;
#pragma unroll
        for (int r = 0; r < 4; r++) {
            const int row = rbase + r;
            if (row < N_NODES) {
                if (col < 64) {
                    int h = col >> 5;
                    t1h[(size_t)h * N_NODES * 32 + (size_t)row * 32 + (col & 31)] = f2bf(acc[nf][r]);
                } else {
                    acc1[(size_t)row * 64 + (col - 64)] = acc[nf][r] + brel[col - 64];
                }
            }
        }
    }
}

// ---------------------------------------------------------------------------
// k_dualf2: t2(bf16)/acc2(f32) from lrelu(acc1)  (K=64, N=64)
// ---------------------------------------------------------------------------
__launch_bounds__(256, 2)
__global__ void k_dualf2(const float* __restrict__ A, const u16* __restrict__ Wf,
                         const float* __restrict__ brel,
                         u16* __restrict__ t2, float* __restrict__ acc2)
{
    const int t = threadIdx.x, wave = t >> 6, lane = t & 63;
    const int lrow = lane & 15, lgrp = lane >> 4;
    const int arow = blockIdx.x * 64 + wave * 16 + lrow;
    const float* ap = A + (size_t)(arow < N_NODES ? arow : 0) * 64 + 8 * lgrp;
    const u16* bp = Wf + lane * 8;

    float4 a00 = *(const float4*)(ap + 0);
    float4 a01 = *(const float4*)(ap + 4);
    float4 a10 = *(const float4*)(ap + 32);
    float4 a11 = *(const float4*)(ap + 36);

    f32x4 acc[4];
#pragma unroll
    for (int i = 0; i < 4; i++) acc[i] = (f32x4)0.f;

    a00.x = lrelu(a00.x); a00.y = lrelu(a00.y); a00.z = lrelu(a00.z); a00.w = lrelu(a00.w);
    a01.x = lrelu(a01.x); a01.y = lrelu(a01.y); a01.z = lrelu(a01.z); a01.w = lrelu(a01.w);
    bf16x8 af0 = cvt8(a00, a01);
    a10.x = lrelu(a10.x); a10.y = lrelu(a10.y); a10.z = lrelu(a10.z); a10.w = lrelu(a10.w);
    a11.x = lrelu(a11.x); a11.y = lrelu(a11.y); a11.z = lrelu(a11.z); a11.w = lrelu(a11.w);
    bf16x8 af1 = cvt8(a10, a11);

#pragma unroll
    for (int nf = 0; nf < 4; nf++) {
        bf16x8 b0 = *(const bf16x8*)(bp + nf * 512);
        bf16x8 b1 = *(const bf16x8*)(bp + 2048 + nf * 512);
        acc[nf] = __builtin_amdgcn_mfma_f32_16x16x32_bf16(af0, b0, acc[nf], 0, 0, 0);
        acc[nf] = __builtin_amdgcn_mfma_f32_16x16x32_bf16(af1, b1, acc[nf], 0, 0, 0);
    }

    const int rbase = blockIdx.x * 64 + wave * 16 + lgrp * 4;
#pragma unroll
    for (int nf = 0; nf < 4; nf++) {
        const int col = nf * 16 + lrow;
#pragma unroll
        for (int r = 0; r < 4; r++) {
            const int row = rbase + r;
            if (row < N_NODES) {
                if (col < 32) t2[(size_t)row * 32 + col] = f2bf(acc[nf][r]);
                else          acc2[(size_t)row * 32 + (col - 32)] = acc[nf][r] + brel[col - 32];
            }
        }
    }
}

// ---------------------------------------------------------------------------
// CSR build
// ---------------------------------------------------------------------------
__launch_bounds__(256)
__global__ void k_zero(int* __restrict__ p, int n)
{
    int i = blockIdx.x * 256 + threadIdx.x;
    if (i < n) p[i] = 0;
}

__launch_bounds__(256)
__global__ void k_hist(const int* __restrict__ ei, int* __restrict__ deg)
{
    const int stride = gridDim.x * 256;
    for (int e = blockIdx.x * 256 + threadIdx.x; e < N_EDGES; e += stride)
        atomicAdd(deg + ei[N_EDGES + e], 1);
}

__launch_bounds__(256)
__global__ void k_scan1(const int* __restrict__ deg, int* __restrict__ tmp,
                        int* __restrict__ bsum)
{
    __shared__ int sm[256];
    const int tid = threadIdx.x;
    const int i = blockIdx.x * 256 + tid;
    int d = (i < N_NODES) ? deg[i] : 0;
    sm[tid] = d;
    __syncthreads();
#pragma unroll
    for (int off = 1; off < 256; off <<= 1) {
        int v = (tid >= off) ? sm[tid - off] : 0;
        __syncthreads();
        sm[tid] += v;
        __syncthreads();
    }
    if (i < N_NODES) tmp[i] = sm[tid];
    if (tid == 255) bsum[blockIdx.x] = sm[255];
}

__launch_bounds__(256)
__global__ void k_scan2p(const int* __restrict__ bsum, int* __restrict__ boff, int nb)
{
    __shared__ int sm[256];
    const int tid = threadIdx.x;
    int v = (tid < nb) ? bsum[tid] : 0;
    sm[tid] = v;
    __syncthreads();
#pragma unroll
    for (int off = 1; off < 256; off <<= 1) {
        int u = (tid >= off) ? sm[tid - off] : 0;
        __syncthreads();
        sm[tid] += u;
        __syncthreads();
    }
    if (tid < nb) boff[tid] = sm[tid] - v;
}

__launch_bounds__(256)
__global__ void k_scan3(const int* __restrict__ tmp, const int* __restrict__ boff,
                        const int* __restrict__ deg, int* __restrict__ ro,
                        int* __restrict__ cur)
{
    const int i = blockIdx.x * 256 + threadIdx.x;
    if (i < N_NODES) {
        int incl = tmp[i] + boff[i >> 8];
        ro[i + 1] = incl;
        cur[i] = incl - deg[i];
    }
    if (i == 0) ro[0] = 0;
}

__launch_bounds__(256)
__global__ void k_fill(const int* __restrict__ ei, int* __restrict__ cur,
                       int* __restrict__ csr)
{
    const int stride = gridDim.x * 256;
    for (int e = blockIdx.x * 256 + threadIdx.x; e < N_EDGES; e += stride) {
        const int dst = ei[N_EDGES + e];
        const int p = atomicAdd(cur + dst, 1);
        csr[p] = ei[e];
    }
}

// ---------------------------------------------------------------------------
// k_gath64h: acc1[n][hsel*32 + f] += sum over in-edges of t1h[hsel][src][f]
// half working set = 3.2 MB -> per-XCD-L2 resident. Wave/node, 2 edges/iter.
// ---------------------------------------------------------------------------
__launch_bounds__(256)
__global__ void k_gath64h(const int* __restrict__ ro, const int* __restrict__ csr,
                          const u16* __restrict__ th, float* __restrict__ acc, int hsel)
{
    const int wid = (blockIdx.x << 2) | (threadIdx.x >> 6);
    if (wid >= N_NODES) return;
    const int lane = threadIdx.x & 63;
    const int half = lane >> 5, f = lane & 31;
    const int s = ro[wid], e = ro[wid + 1];
    float a = 0.f;
    int i = s;
    for (; i + 8 <= e; i += 8) {
        int s0 = csr[i + half], s1 = csr[i + 2 + half];
        int s2 = csr[i + 4 + half], s3 = csr[i + 6 + half];
        u16 v0 = th[(size_t)s0 * 32 + f], v1 = th[(size_t)s1 * 32 + f];
        u16 v2 = th[(size_t)s2 * 32 + f], v3 = th[(size_t)s3 * 32 + f];
        a += bf2f(v0); a += bf2f(v1); a += bf2f(v2); a += bf2f(v3);
    }
    for (; i < e; i += 2) {
        int idx = i + half;
        if (idx < e) a += bf2f(th[(size_t)csr[idx] * 32 + f]);
    }
    a += __shfl_xor(a, 32, 64);
    if (half == 0) acc[(size_t)wid * 64 + hsel * 32 + f] += a;
}

// ---------------------------------------------------------------------------
// k_gpos: fused gather32 + lrelu + pos GEMV
// ---------------------------------------------------------------------------
__launch_bounds__(256)
__global__ void k_gpos(const int* __restrict__ ro, const int* __restrict__ csr,
                       const u16* __restrict__ t, const float* __restrict__ acc2,
                       const float* __restrict__ PW, const float* __restrict__ PB,
                       float* __restrict__ out)
{
    const int wid = (blockIdx.x << 2) | (threadIdx.x >> 6);
    if (wid >= N_NODES) return;
    const int lane = threadIdx.x & 63;
    const int half = lane >> 5, f = lane & 31;
    const int s = ro[wid], e = ro[wid + 1];
    float a = 0.f;
    int i = s;
    for (; i + 8 <= e; i += 8) {
        int s0 = csr[i + half], s1 = csr[i + 2 + half];
        int s2 = csr[i + 4 + half], s3 = csr[i + 6 + half];
        u16 v0 = t[(size_t)s0 * 32 + f], v1 = t[(size_t)s1 * 32 + f];
        u16 v2 = t[(size_t)s2 * 32 + f], v3 = t[(size_t)s3 * 32 + f];
        a += bf2f(v0); a += bf2f(v1); a += bf2f(v2); a += bf2f(v3);
    }
    for (; i < e; i += 2) {
        int idx = i + half;
        if (idx < e) a += bf2f(t[(size_t)csr[idx] * 32 + f]);
    }
    a += __shfl_xor(a, 32, 64);

    float v = lrelu(acc2[(size_t)wid * 32 + f] + a);
    float p0 = v * PW[f], p1 = v * PW[32 + f], p2 = v * PW[64 + f];
#pragma unroll
    for (int off = 16; off >= 1; off >>= 1) {
        p0 += __shfl_xor(p0, off, 64);
        p1 += __shfl_xor(p1, off, 64);
        p2 += __shfl_xor(p2, off, 64);
    }
    if (lane == 0) {
        out[(size_t)wid * 3 + 0] = p0 + PB[0];
        out[(size_t)wid * 3 + 1] = p1 + PB[1];
        out[(size_t)wid * 3 + 2] = p2 + PB[2];
    }
}

// ---------------------------------------------------------------------------
extern "C" void kernel_launch(void* const* d_in, const int* in_sizes, int n_in,
                              void* d_out, int out_size, void* d_ws, size_t ws_size,
                              hipStream_t stream)
{
    const float* x        = (const float*)d_in[0];
    const int*   ei       = (const int*)d_in[1];
    const float* lin1_w   = (const float*)d_in[2];
    const float* lin1_b   = (const float*)d_in[3];
    const float* c1_wrel  = (const float*)d_in[4];
    const float* c1_brel  = (const float*)d_in[5];
    const float* c1_wroot = (const float*)d_in[6];
    const float* c4_wrel  = (const float*)d_in[7];
    const float* c4_brel  = (const float*)d_in[8];
    const float* c4_wroot = (const float*)d_in[9];
    const float* pos_w    = (const float*)d_in[10];
    const float* pos_b    = (const float*)d_in[11];
    float* out = (float*)d_out;

    char* base = (char*)d_ws;
    u16*   h1b  = (u16*)base;                                   // 12.8 MB
    u16*   t1h  = (u16*)(base + 12800000);                      // 2 x [N][32] bf16 = 6.4 MB
    float* acc1 = (float*)(base + 12800000 + 6400000);          // 12.8 MB
    u16*   t2b  = (u16*)(base + 32000000);                      // 3.2 MB
    float* acc2 = (float*)(base + 35200000);                    // 6.4 MB
    u16*   wf1  = (u16*)(base + 41600000);                      // 512 KB
    u16*   wf2  = wf1 + 262144;
    u16*   wf3  = wf2 + 16384;
    int*   ibase = (int*)(wf3 + 4096);
    const int NPAD = ((N_NODES + 255) / 256) * 256;             // 50176
    int* deg  = ibase;
    int* tmp  = deg  + NPAD;
    int* ro   = tmp  + NPAD;
    int* cur  = ro   + NPAD;
    int* bsum = cur  + NPAD;
    int* boff = bsum + 256;
    int* csr  = boff + 256;
    const int NB = (N_NODES + 255) / 256;                       // 196

    // weight prep (merged)
    hipLaunchKernelGGL(k_wprep, dim3(1104), dim3(256), 0, stream,
                       lin1_w, c1_wrel, c1_wroot, c4_wrel, c4_wroot, wf1, wf2, wf3);

    // CSR build
    hipLaunchKernelGGL(k_zero, dim3(NB), dim3(256), 0, stream, deg, N_NODES);
    hipLaunchKernelGGL(k_hist, dim3(2048), dim3(256), 0, stream, ei, deg);
    hipLaunchKernelGGL(k_scan1, dim3(NB), dim3(256), 0, stream, deg, tmp, bsum);
    hipLaunchKernelGGL(k_scan2p, dim3(1), dim3(256), 0, stream, bsum, boff, NB);
    hipLaunchKernelGGL(k_scan3, dim3(NB), dim3(256), 0, stream, tmp, boff, deg, ro, cur);
    hipLaunchKernelGGL(k_fill, dim3(2048), dim3(256), 0, stream, ei, cur, csr);

    // 1) h1(bf16) = lrelu(x @ lin1_w.T + b)   [counted-vmcnt pipelined GEMM]
    hipLaunchKernelGGL(k_lin1p, dim3((N_NODES + 63) / 64), dim3(256), 0, stream,
                       x, wf1, lin1_b, h1b);
    // 2) t1 halves / acc1
    hipLaunchKernelGGL(k_dualf1, dim3((N_NODES + 63) / 64), dim3(256), 0, stream,
                       h1b, wf2, c1_brel, t1h, acc1);
    // 3) acc1 += gather(t1), per-half so working set fits per-XCD L2
    hipLaunchKernelGGL(k_gath64h, dim3((N_NODES + 3) / 4), dim3(256), 0, stream,
                       ro, csr, t1h, acc1, 0);
    hipLaunchKernelGGL(k_gath64h, dim3((N_NODES + 3) / 4), dim3(256), 0, stream,
                       ro, csr, t1h + (size_t)N_NODES * 32, acc1, 1);
    // 4) t2(bf16) / acc2(f32)
    hipLaunchKernelGGL(k_dualf2, dim3((N_NODES + 63) / 64), dim3(256), 0, stream,
                       acc1, wf3, c4_brel, t2b, acc2);
    // 5) out = lrelu(acc2 + gather(t2)) @ pos_w.T + pos_b
    hipLaunchKernelGGL(k_gpos, dim3((N_NODES + 3) / 4), dim3(256), 0, stream,
                       ro, csr, t2b, acc2, pos_w, pos_b, out);
}

// Round 7
// 440.976 us; speedup vs baseline: 1.0675x; 1.0675x over previous
//
#include <hip/hip_runtime.h>

#define N_NODES 50000
#define N_EDGES 1600000

typedef __attribute__((ext_vector_type(4))) float f32x4;
typedef __attribute__((ext_vector_type(8))) short bf16x8;
typedef unsigned short u16;

__device__ __forceinline__ float lrelu(float x) { return x >= 0.f ? x : 0.01f * x; }

__device__ __forceinline__ u16 f2bf(float f) {
    union { float f; unsigned u; } v; v.f = f;
    unsigned u = v.u;
    u += 0x7fffu + ((u >> 16) & 1u);
    return (u16)(u >> 16);
}

__device__ __forceinline__ float bf2f(u16 v) {
    union { unsigned u; float f; } x; x.u = ((unsigned)v) << 16; return x.f;
}

__device__ __forceinline__ bf16x8 cvt8(float4 a, float4 b) {
    bf16x8 r;
    r[0] = (short)f2bf(a.x); r[1] = (short)f2bf(a.y);
    r[2] = (short)f2bf(a.z); r[3] = (short)f2bf(a.w);
    r[4] = (short)f2bf(b.x); r[5] = (short)f2bf(b.y);
    r[6] = (short)f2bf(b.z); r[7] = (short)f2bf(b.w);
    return r;
}

__device__ __forceinline__ void gload_lds16(const void* g, void* l) {
    __builtin_amdgcn_global_load_lds(
        (const __attribute__((address_space(1))) void*)g,
        (__attribute__((address_space(3))) void*)l, 16, 0, 0);
}

// ---------------------------------------------------------------------------
// k_prep: fragment-ordered bf16 weight tables + deg zeroing, one kernel.
// Wf layout: [kstep][nf][lane][8]; elem = W[nf*16+(lane&15)][ks*32+8*(lane>>4)+e]
// ---------------------------------------------------------------------------
__launch_bounds__(256)
__global__ void k_prep(const float* __restrict__ W1,
                       const float* __restrict__ W2a, const float* __restrict__ W2b,
                       const float* __restrict__ W3a, const float* __restrict__ W3b,
                       u16* __restrict__ wf1, u16* __restrict__ wf2, u16* __restrict__ wf3,
                       int* __restrict__ deg)
{
    const int b = blockIdx.x;
    if (b < 1024) {
        int i = b * 256 + threadIdx.x;
        int e = i & 7, lane = (i >> 3) & 63, nf = (i >> 9) & 7, ks = i >> 12;
        int n = nf * 16 + (lane & 15);
        int k = ks * 32 + 8 * (lane >> 4) + e;
        wf1[i] = f2bf(W1[(size_t)n * 2048 + k]);
    } else if (b < 1088) {
        int i = (b - 1024) * 256 + threadIdx.x;
        int e = i & 7, lane = (i >> 3) & 63, nf = (i >> 9) & 7, ks = i >> 12;
        int n = nf * 16 + (lane & 15);
        int k = ks * 32 + 8 * (lane >> 4) + e;
        float v = (n < 64) ? W2a[(size_t)n * 128 + k] : W2b[(size_t)(n - 64) * 128 + k];
        wf2[i] = f2bf(v);
    } else if (b < 1104) {
        int i = (b - 1088) * 256 + threadIdx.x;
        int e = i & 7, lane = (i >> 3) & 63, nf = (i >> 9) & 3, ks = i >> 11;
        int n = nf * 16 + (lane & 15);
        int k = ks * 32 + 8 * (lane >> 4) + e;
        float v = (n < 32) ? W3a[(size_t)n * 64 + k] : W3b[(size_t)(n - 32) * 64 + k];
        wf3[i] = f2bf(v);
    } else {
        int i = (b - 1104) * 256 + threadIdx.x;
        if (i < N_NODES) deg[i] = 0;
    }
}

// ---------------------------------------------------------------------------
// k_lin1d: FUSED  h1 = lrelu(x @ lin1_w.T + b)  ->  t1 = h1 @ c1_wrel.T ,
//                 acc1 = h1 @ c1_wroot.T + b_rel.   h1 never touches HBM.
// Main GEMM: BM=64, BK=32, 3-slot LDS ring (48KB -> 3 blocks/CU), counted
// vmcnt(8) (4 gload_lds16/thread/stage, 3 stages in flight, never 0 in-loop).
// Slot: A[64r][32k f32, 16B-granule XOR swz] 8KB + B[8KB wf1 slice].
// Epilogue: wave-private h-tile [16][128]bf16 in slot-1 region (dead after
// s=62 barrier), granule-swizzled; dual GEMM K=128 from it, B from wf2 (L2).
// ---------------------------------------------------------------------------
__device__ __forceinline__ void stage_step(const float* __restrict__ X,
                                           const u16* __restrict__ Wf,
                                           char* slot, int m0, int s, int t)
{
    const int wave = t >> 6, l = t & 63;
    const int j = l >> 3, g = l & 7;
#pragma unroll
    for (int r = 0; r < 2; r++) {
        int lrow = r * 32 + wave * 8 + j;
        int grow = m0 + lrow; if (grow >= N_NODES) grow = N_NODES - 1;
        const float* srcA = X + (size_t)grow * 2048 + s * 32 + (((g ^ j) * 16) >> 2);
        gload_lds16(srcA, slot + r * 4096 + wave * 1024);
    }
#pragma unroll
    for (int r = 0; r < 2; r++) {
        const u16* srcB = Wf + (size_t)s * 4096 + (size_t)(r * 256 + t) * 8;
        gload_lds16(srcB, slot + 8192 + r * 4096 + wave * 1024);
    }
}

__device__ __forceinline__ void compute_step(const char* slot, int lane, int wave,
                                             f32x4 acc[8])
{
    const int lrow = lane & 15, lgrp = lane >> 4;
    const int row = wave * 16 + lrow;
    const int swz = (row & 7) << 4;
    const char* Ab = slot + row * 128;
    float4 a0 = *(const float4*)(Ab + ((lgrp * 32) ^ swz));
    float4 a1 = *(const float4*)(Ab + ((lgrp * 32 + 16) ^ swz));
    bf16x8 af = cvt8(a0, a1);
    const char* Bb = slot + 8192 + lane * 16;
    __builtin_amdgcn_s_setprio(1);
#pragma unroll
    for (int nf = 0; nf < 8; nf++) {
        bf16x8 bf = *(const bf16x8*)(Bb + nf * 1024);
        acc[nf] = __builtin_amdgcn_mfma_f32_16x16x32_bf16(af, bf, acc[nf], 0, 0, 0);
    }
    __builtin_amdgcn_s_setprio(0);
}

__launch_bounds__(256, 3)
__global__ void k_lin1d(const float* __restrict__ X, const u16* __restrict__ Wf1,
                        const u16* __restrict__ Wf2,
                        const float* __restrict__ Bv, const float* __restrict__ brel,
                        u16* __restrict__ t1, float* __restrict__ acc1)
{
    __shared__ __align__(16) char lds[3][16384];
    const int t = threadIdx.x, wave = t >> 6, lane = t & 63;
    const int lrow = lane & 15, lgrp = lane >> 4;
    const int m0 = blockIdx.x * 64;

    f32x4 acc[8];
#pragma unroll
    for (int i = 0; i < 8; i++) acc[i] = (f32x4)0.f;

    stage_step(X, Wf1, lds[0], m0, 0, t);
    stage_step(X, Wf1, lds[1], m0, 1, t);
    stage_step(X, Wf1, lds[2], m0, 2, t);

    for (int s = 0; s < 61; s++) {
        asm volatile("s_waitcnt vmcnt(8)" ::: "memory");
        __builtin_amdgcn_s_barrier();
        compute_step(lds[0] + (s % 3) * 16384, lane, wave, acc);
        __builtin_amdgcn_s_barrier();
        stage_step(X, Wf1, lds[0] + (s % 3) * 16384, m0, s + 3, t);
    }
    // peeled tail: stages 61..63 in flight, no further staging
    asm volatile("s_waitcnt vmcnt(8)" ::: "memory");
    __builtin_amdgcn_s_barrier();
    compute_step(lds[1], lane, wave, acc);          // s=61 (slot 1)
    asm volatile("s_waitcnt vmcnt(4)" ::: "memory");
    __builtin_amdgcn_s_barrier();                   // all waves done reading slot 1
    compute_step(lds[2], lane, wave, acc);          // s=62 (slot 2)
    asm volatile("s_waitcnt vmcnt(0)" ::: "memory");
    __builtin_amdgcn_s_barrier();
    compute_step(lds[0], lane, wave, acc);          // s=63 (slot 0)

    // ---- fused dual GEMM epilogue ----
    // wave-private h-tile [16 rows][128 cols] bf16 in slot-1 region.
    // write: h[row][col] -> idx = row*128 + ((col>>3)^(row&7))*8 + (col&7)
    u16* hl = (u16*)(lds[1] + wave * 4096);
#pragma unroll
    for (int nf = 0; nf < 8; nf++) {
        const int col = nf * 16 + lrow;
        const float bias = Bv[col];
#pragma unroll
        for (int r = 0; r < 4; r++) {
            const int row = lgrp * 4 + r;
            hl[row * 128 + (((col >> 3) ^ (row & 7)) << 3) + (col & 7)] =
                f2bf(lrelu(acc[nf][r] + bias));
        }
    }
    // read A-frags: lane holds h[lrow][ks*32 + 8*lgrp + e]
    bf16x8 af2[4];
#pragma unroll
    for (int ks = 0; ks < 4; ks++)
        af2[ks] = *(const bf16x8*)(hl + lrow * 128 + ((((ks << 2) + lgrp) ^ (lrow & 7)) << 3));

    f32x4 dacc[8];
#pragma unroll
    for (int i = 0; i < 8; i++) dacc[i] = (f32x4)0.f;
    const u16* bp2 = Wf2 + lane * 8;
#pragma unroll
    for (int ks = 0; ks < 4; ks++) {
#pragma unroll
        for (int nf = 0; nf < 8; nf++) {
            bf16x8 bf = *(const bf16x8*)(bp2 + ks * 4096 + nf * 512);
            dacc[nf] = __builtin_amdgcn_mfma_f32_16x16x32_bf16(af2[ks], bf, dacc[nf], 0, 0, 0);
        }
    }

    const int rbase = m0 + wave * 16 + lgrp * 4;
#pragma unroll
    for (int nf = 0; nf < 8; nf++) {
        const int col = nf * 16 + lrow;
#pragma unroll
        for (int r = 0; r < 4; r++) {
            const int row = rbase + r;
            if (row < N_NODES) {
                if (col < 64) t1[(size_t)row * 64 + col] = f2bf(dacc[nf][r]);
                else          acc1[(size_t)row * 64 + (col - 64)] = dacc[nf][r] + brel[col - 64];
            }
        }
    }
}

// ---------------------------------------------------------------------------
// k_dualf2: t2(bf16)/acc2(f32) from lrelu(acc1)  (K=64, N=64)
// ---------------------------------------------------------------------------
__launch_bounds__(256, 2)
__global__ void k_dualf2(const float* __restrict__ A, const u16* __restrict__ Wf,
                         const float* __restrict__ brel,
                         u16* __restrict__ t2, float* __restrict__ acc2)
{
    const int t = threadIdx.x, wave = t >> 6, lane = t & 63;
    const int lrow = lane & 15, lgrp = lane >> 4;
    const int arow = blockIdx.x * 64 + wave * 16 + lrow;
    const float* ap = A + (size_t)(arow < N_NODES ? arow : 0) * 64 + 8 * lgrp;
    const u16* bp = Wf + lane * 8;

    float4 a00 = *(const float4*)(ap + 0);
    float4 a01 = *(const float4*)(ap + 4);
    float4 a10 = *(const float4*)(ap + 32);
    float4 a11 = *(const float4*)(ap + 36);

    f32x4 acc[4];
#pragma unroll
    for (int i = 0; i < 4; i++) acc[i] = (f32x4)0.f;

    a00.x = lrelu(a00.x); a00.y = lrelu(a00.y); a00.z = lrelu(a00.z); a00.w = lrelu(a00.w);
    a01.x = lrelu(a01.x); a01.y = lrelu(a01.y); a01.z = lrelu(a01.z); a01.w = lrelu(a01.w);
    bf16x8 af0 = cvt8(a00, a01);
    a10.x = lrelu(a10.x); a10.y = lrelu(a10.y); a10.z = lrelu(a10.z); a10.w = lrelu(a10.w);
    a11.x = lrelu(a11.x); a11.y = lrelu(a11.y); a11.z = lrelu(a11.z); a11.w = lrelu(a11.w);
    bf16x8 af1 = cvt8(a10, a11);

#pragma unroll
    for (int nf = 0; nf < 4; nf++) {
        bf16x8 b0 = *(const bf16x8*)(bp + nf * 512);
        bf16x8 b1 = *(const bf16x8*)(bp + 2048 + nf * 512);
        acc[nf] = __builtin_amdgcn_mfma_f32_16x16x32_bf16(af0, b0, acc[nf], 0, 0, 0);
        acc[nf] = __builtin_amdgcn_mfma_f32_16x16x32_bf16(af1, b1, acc[nf], 0, 0, 0);
    }

    const int rbase = blockIdx.x * 64 + wave * 16 + lgrp * 4;
#pragma unroll
    for (int nf = 0; nf < 4; nf++) {
        const int col = nf * 16 + lrow;
#pragma unroll
        for (int r = 0; r < 4; r++) {
            const int row = rbase + r;
            if (row < N_NODES) {
                if (col < 32) t2[(size_t)row * 32 + col] = f2bf(acc[nf][r]);
                else          acc2[(size_t)row * 32 + (col - 32)] = acc[nf][r] + brel[col - 32];
            }
        }
    }
}

// ---------------------------------------------------------------------------
// CSR build
// ---------------------------------------------------------------------------
__launch_bounds__(256)
__global__ void k_hist(const int* __restrict__ ei, int* __restrict__ deg)
{
    const int stride = gridDim.x * 256;
    for (int e = blockIdx.x * 256 + threadIdx.x; e < N_EDGES; e += stride)
        atomicAdd(deg + ei[N_EDGES + e], 1);
}

__launch_bounds__(256)
__global__ void k_scan1(const int* __restrict__ deg, int* __restrict__ tmp,
                        int* __restrict__ bsum)
{
    __shared__ int sm[256];
    const int tid = threadIdx.x;
    const int i = blockIdx.x * 256 + tid;
    int d = (i < N_NODES) ? deg[i] : 0;
    sm[tid] = d;
    __syncthreads();
#pragma unroll
    for (int off = 1; off < 256; off <<= 1) {
        int v = (tid >= off) ? sm[tid - off] : 0;
        __syncthreads();
        sm[tid] += v;
        __syncthreads();
    }
    if (i < N_NODES) tmp[i] = sm[tid];
    if (tid == 255) bsum[blockIdx.x] = sm[255];
}

__launch_bounds__(256)
__global__ void k_scan2p(const int* __restrict__ bsum, int* __restrict__ boff, int nb)
{
    __shared__ int sm[256];
    const int tid = threadIdx.x;
    int v = (tid < nb) ? bsum[tid] : 0;
    sm[tid] = v;
    __syncthreads();
#pragma unroll
    for (int off = 1; off < 256; off <<= 1) {
        int u = (tid >= off) ? sm[tid - off] : 0;
        __syncthreads();
        sm[tid] += u;
        __syncthreads();
    }
    if (tid < nb) boff[tid] = sm[tid] - v;
}

__launch_bounds__(256)
__global__ void k_scan3(const int* __restrict__ tmp, const int* __restrict__ boff,
                        const int* __restrict__ deg, int* __restrict__ ro,
                        int* __restrict__ cur)
{
    const int i = blockIdx.x * 256 + threadIdx.x;
    if (i < N_NODES) {
        int incl = tmp[i] + boff[i >> 8];
        ro[i + 1] = incl;
        cur[i] = incl - deg[i];
    }
    if (i == 0) ro[0] = 0;
}

__launch_bounds__(256)
__global__ void k_fill(const int* __restrict__ ei, int* __restrict__ cur,
                       int* __restrict__ csr)
{
    const int stride = gridDim.x * 256;
    for (int e = blockIdx.x * 256 + threadIdx.x; e < N_EDGES; e += stride) {
        const int dst = ei[N_EDGES + e];
        const int p = atomicAdd(cur + dst, 1);
        csr[p] = ei[e];
    }
}

// ---------------------------------------------------------------------------
// k_gather64: acc1[n] += sum over in-edges of t1(bf16)[src]; wave/node
// ---------------------------------------------------------------------------
__launch_bounds__(256)
__global__ void k_gather64(const int* __restrict__ ro, const int* __restrict__ csr,
                           const u16* __restrict__ t, float* __restrict__ acc)
{
    const int wid = (blockIdx.x << 2) | (threadIdx.x >> 6);
    if (wid >= N_NODES) return;
    const int lane = threadIdx.x & 63;
    const int s = ro[wid], e = ro[wid + 1];
    float a = acc[(size_t)wid * 64 + lane];
    int i = s;
    for (; i + 8 <= e; i += 8) {
        int s0 = csr[i], s1 = csr[i + 1], s2 = csr[i + 2], s3 = csr[i + 3];
        int s4 = csr[i + 4], s5 = csr[i + 5], s6 = csr[i + 6], s7 = csr[i + 7];
        u16 v0 = t[(size_t)s0 * 64 + lane], v1 = t[(size_t)s1 * 64 + lane];
        u16 v2 = t[(size_t)s2 * 64 + lane], v3 = t[(size_t)s3 * 64 + lane];
        u16 v4 = t[(size_t)s4 * 64 + lane], v5 = t[(size_t)s5 * 64 + lane];
        u16 v6 = t[(size_t)s6 * 64 + lane], v7 = t[(size_t)s7 * 64 + lane];
        a += bf2f(v0); a += bf2f(v1); a += bf2f(v2); a += bf2f(v3);
        a += bf2f(v4); a += bf2f(v5); a += bf2f(v6); a += bf2f(v7);
    }
    for (; i < e; ++i) a += bf2f(t[(size_t)csr[i] * 64 + lane]);
    acc[(size_t)wid * 64 + lane] = a;
}

// ---------------------------------------------------------------------------
// k_gpos: fused gather32 + lrelu + pos GEMV
// ---------------------------------------------------------------------------
__launch_bounds__(256)
__global__ void k_gpos(const int* __restrict__ ro, const int* __restrict__ csr,
                       const u16* __restrict__ t, const float* __restrict__ acc2,
                       const float* __restrict__ PW, const float* __restrict__ PB,
                       float* __restrict__ out)
{
    const int wid = (blockIdx.x << 2) | (threadIdx.x >> 6);
    if (wid >= N_NODES) return;
    const int lane = threadIdx.x & 63;
    const int half = lane >> 5, f = lane & 31;
    const int s = ro[wid], e = ro[wid + 1];
    float a = 0.f;
    int i = s;
    for (; i + 8 <= e; i += 8) {
        int s0 = csr[i + half], s1 = csr[i + 2 + half];
        int s2 = csr[i + 4 + half], s3 = csr[i + 6 + half];
        u16 v0 = t[(size_t)s0 * 32 + f], v1 = t[(size_t)s1 * 32 + f];
        u16 v2 = t[(size_t)s2 * 32 + f], v3 = t[(size_t)s3 * 32 + f];
        a += bf2f(v0); a += bf2f(v1); a += bf2f(v2); a += bf2f(v3);
    }
    for (; i < e; i += 2) {
        int idx = i + half;
        if (idx < e) a += bf2f(t[(size_t)csr[idx] * 32 + f]);
    }
    a += __shfl_xor(a, 32, 64);

    float v = lrelu(acc2[(size_t)wid * 32 + f] + a);
    float p0 = v * PW[f], p1 = v * PW[32 + f], p2 = v * PW[64 + f];
#pragma unroll
    for (int off = 16; off >= 1; off >>= 1) {
        p0 += __shfl_xor(p0, off, 64);
        p1 += __shfl_xor(p1, off, 64);
        p2 += __shfl_xor(p2, off, 64);
    }
    if (lane == 0) {
        out[(size_t)wid * 3 + 0] = p0 + PB[0];
        out[(size_t)wid * 3 + 1] = p1 + PB[1];
        out[(size_t)wid * 3 + 2] = p2 + PB[2];
    }
}

// ---------------------------------------------------------------------------
extern "C" void kernel_launch(void* const* d_in, const int* in_sizes, int n_in,
                              void* d_out, int out_size, void* d_ws, size_t ws_size,
                              hipStream_t stream)
{
    const float* x        = (const float*)d_in[0];
    const int*   ei       = (const int*)d_in[1];
    const float* lin1_w   = (const float*)d_in[2];
    const float* lin1_b   = (const float*)d_in[3];
    const float* c1_wrel  = (const float*)d_in[4];
    const float* c1_brel  = (const float*)d_in[5];
    const float* c1_wroot = (const float*)d_in[6];
    const float* c4_wrel  = (const float*)d_in[7];
    const float* c4_brel  = (const float*)d_in[8];
    const float* c4_wroot = (const float*)d_in[9];
    const float* pos_w    = (const float*)d_in[10];
    const float* pos_b    = (const float*)d_in[11];
    float* out = (float*)d_out;

    char* base = (char*)d_ws;
    u16*   t1b  = (u16*)base;                        // [N][64] bf16 = 6.4 MB
    float* acc1 = (float*)(base + 6400000);          // [N][64] f32  = 12.8 MB
    u16*   t2b  = (u16*)(base + 19200000);           // [N][32] bf16 = 3.2 MB
    float* acc2 = (float*)(base + 22400000);         // [N][32] f32  = 6.4 MB
    u16*   wf1  = (u16*)(base + 28800000);           // 512 KB
    u16*   wf2  = wf1 + 262144;                      // 32 KB
    u16*   wf3  = wf2 + 16384;                       // 8 KB
    int*   ibase = (int*)(wf3 + 4096);
    const int NPAD = ((N_NODES + 255) / 256) * 256;  // 50176
    int* deg  = ibase;
    int* tmp  = deg  + NPAD;
    int* ro   = tmp  + NPAD;
    int* cur  = ro   + NPAD;
    int* bsum = cur  + NPAD;
    int* boff = bsum + 256;
    int* csr  = boff + 256;
    const int NB = (N_NODES + 255) / 256;            // 196

    // weight tables + deg zero (one kernel)
    hipLaunchKernelGGL(k_prep, dim3(1104 + NB), dim3(256), 0, stream,
                       lin1_w, c1_wrel, c1_wroot, c4_wrel, c4_wroot,
                       wf1, wf2, wf3, deg);
    // CSR build
    hipLaunchKernelGGL(k_hist, dim3(2048), dim3(256), 0, stream, ei, deg);
    hipLaunchKernelGGL(k_scan1, dim3(NB), dim3(256), 0, stream, deg, tmp, bsum);
    hipLaunchKernelGGL(k_scan2p, dim3(1), dim3(256), 0, stream, bsum, boff, NB);
    hipLaunchKernelGGL(k_scan3, dim3(NB), dim3(256), 0, stream, tmp, boff, deg, ro, cur);
    hipLaunchKernelGGL(k_fill, dim3(2048), dim3(256), 0, stream, ei, cur, csr);

    // 1+2) fused: h1 (in-LDS) -> t1(bf16) / acc1(f32)
    hipLaunchKernelGGL(k_lin1d, dim3((N_NODES + 63) / 64), dim3(256), 0, stream,
                       x, wf1, wf2, lin1_b, c1_brel, t1b, acc1);
    // 3) acc1 += gather(t1)
    hipLaunchKernelGGL(k_gather64, dim3((N_NODES + 3) / 4), dim3(256), 0, stream,
                       ro, csr, t1b, acc1);
    // 4) t2(bf16) / acc2(f32)
    hipLaunchKernelGGL(k_dualf2, dim3((N_NODES + 63) / 64), dim3(256), 0, stream,
                       acc1, wf3, c4_brel, t2b, acc2);
    // 5) out = lrelu(acc2 + gather(t2)) @ pos_w.T + pos_b
    hipLaunchKernelGGL(k_gpos, dim3((N_NODES + 3) / 4), dim3(256), 0, stream,
                       ro, csr, t2b, acc2, pos_w, pos_b, out);
}

// Round 8
// 369.658 us; speedup vs baseline: 1.2735x; 1.1929x over previous
//
#include <hip/hip_runtime.h>

#define N_NODES 50000
#define N_EDGES 1600000
#define LIN_BLOCKS 782
#define HIST_BLOCKS 1024

typedef __attribute__((ext_vector_type(4))) float f32x4;
typedef __attribute__((ext_vector_type(8))) short bf16x8;
typedef unsigned short u16;

__device__ __forceinline__ float lrelu(float x) { return x >= 0.f ? x : 0.01f * x; }

__device__ __forceinline__ u16 f2bf(float f) {
    union { float f; unsigned u; } v; v.f = f;
    unsigned u = v.u;
    u += 0x7fffu + ((u >> 16) & 1u);
    return (u16)(u >> 16);
}

__device__ __forceinline__ float bf2f(u16 v) {
    union { unsigned u; float f; } x; x.u = ((unsigned)v) << 16; return x.f;
}

__device__ __forceinline__ bf16x8 cvt8(float4 a, float4 b) {
    bf16x8 r;
    r[0] = (short)f2bf(a.x); r[1] = (short)f2bf(a.y);
    r[2] = (short)f2bf(a.z); r[3] = (short)f2bf(a.w);
    r[4] = (short)f2bf(b.x); r[5] = (short)f2bf(b.y);
    r[6] = (short)f2bf(b.z); r[7] = (short)f2bf(b.w);
    return r;
}

// ---------------------------------------------------------------------------
// k_prep: fragment-ordered bf16 weight tables + hist (deg pre-zeroed by
// hipMemsetAsync). Wf layout [kstep][nf][lane][8].
// ---------------------------------------------------------------------------
__launch_bounds__(256)
__global__ void k_prep(const float* __restrict__ W1,
                       const float* __restrict__ W2a, const float* __restrict__ W2b,
                       const float* __restrict__ W3a, const float* __restrict__ W3b,
                       u16* __restrict__ wf1, u16* __restrict__ wf2, u16* __restrict__ wf3,
                       const int* __restrict__ ei, int* __restrict__ deg)
{
    const int b = blockIdx.x;
    if (b < 1024) {
        int i = b * 256 + threadIdx.x;
        int e = i & 7, lane = (i >> 3) & 63, nf = (i >> 9) & 7, ks = i >> 12;
        int n = nf * 16 + (lane & 15);
        int k = ks * 32 + 8 * (lane >> 4) + e;
        wf1[i] = f2bf(W1[(size_t)n * 2048 + k]);
    } else if (b < 1088) {
        int i = (b - 1024) * 256 + threadIdx.x;
        int e = i & 7, lane = (i >> 3) & 63, nf = (i >> 9) & 7, ks = i >> 12;
        int n = nf * 16 + (lane & 15);
        int k = ks * 32 + 8 * (lane >> 4) + e;
        float v = (n < 64) ? W2a[(size_t)n * 128 + k] : W2b[(size_t)(n - 64) * 128 + k];
        wf2[i] = f2bf(v);
    } else if (b < 1104) {
        int i = (b - 1088) * 256 + threadIdx.x;
        int e = i & 7, lane = (i >> 3) & 63, nf = (i >> 9) & 3, ks = i >> 11;
        int n = nf * 16 + (lane & 15);
        int k = ks * 32 + 8 * (lane >> 4) + e;
        float v = (n < 32) ? W3a[(size_t)n * 64 + k] : W3b[(size_t)(n - 32) * 64 + k];
        wf3[i] = f2bf(v);
    } else {
        for (int e = (b - 1104) * 256 + threadIdx.x; e < N_EDGES; e += HIST_BLOCKS * 256)
            atomicAdd(deg + ei[N_EDGES + e], 1);
    }
}

// ---------------------------------------------------------------------------
// k_linf: FUSED  h1 = lrelu(x @ lin1_w.T + b) -> t1 = h1 @ c1_wrel.T ,
//                acc1 = h1 @ c1_wroot.T + b_rel ; then CSR-fill tail.
// Reg-staged pipeline (NO global_load_lds): plain dwordx4 loads -> regs ->
// ds_write_b128. 2-slot ping-pong, 2-stage lookahead; compiler inserts
// precise counted vmcnt before each ds_write cluster; barriers are raw
// s_barrier with lgkmcnt(0) only (global loads stay in flight).
// Slot = A[64r][32k f32, 16B-granule XOR swz] 8KB + B[8KB wf1 slice].
// ---------------------------------------------------------------------------
__device__ __forceinline__ void wr_stage(char* slot, int aw0, int aw1, int bw,
                                         float4 A0, float4 A1, float4 B0, float4 B1)
{
    *(float4*)(slot + aw0) = A0;
    *(float4*)(slot + aw1) = A1;
    *(float4*)(slot + bw) = B0;
    *(float4*)(slot + bw + 16) = B1;
}

__device__ __forceinline__ void compute_step(const char* slot, int lane, int wave,
                                             f32x4 acc[8])
{
    const int lrow = lane & 15, lgrp = lane >> 4;
    const int row = wave * 16 + lrow;
    const int swz = (row & 7) << 4;
    const char* Ab = slot + row * 128;
    float4 a0 = *(const float4*)(Ab + ((lgrp * 32) ^ swz));
    float4 a1 = *(const float4*)(Ab + ((lgrp * 32 + 16) ^ swz));
    bf16x8 af = cvt8(a0, a1);
    const char* Bb = slot + 8192 + lane * 16;
    __builtin_amdgcn_s_setprio(1);
#pragma unroll
    for (int nf = 0; nf < 8; nf++) {
        bf16x8 bf = *(const bf16x8*)(Bb + nf * 1024);
        acc[nf] = __builtin_amdgcn_mfma_f32_16x16x32_bf16(af, bf, acc[nf], 0, 0, 0);
    }
    __builtin_amdgcn_s_setprio(0);
}

__launch_bounds__(256, 3)
__global__ void k_linf(const float* __restrict__ X, const u16* __restrict__ Wf1,
                       const u16* __restrict__ Wf2,
                       const float* __restrict__ Bv, const float* __restrict__ brel,
                       u16* __restrict__ t1, float* __restrict__ acc1,
                       const int* __restrict__ ei, int* __restrict__ cur,
                       int* __restrict__ csr)
{
    __shared__ __align__(16) char lds[2][16384];
    __shared__ __align__(16) u16 hlbuf[4][2048];   // 4 waves x [16][128] bf16

    const int t = threadIdx.x, wave = t >> 6, lane = t & 63;
    const int lrow = lane & 15, lgrp = lane >> 4;
    const int m0 = blockIdx.x * 64;

    // staging geometry
    const int arow_l = t >> 2, q = t & 3;
    int grow = m0 + arow_l; if (grow >= N_NODES) grow = N_NODES - 1;
    const float4* ap = (const float4*)(X + (size_t)grow * 2048);   // + s*8 + q*2
    const float4* bp = (const float4*)Wf1;                          // + s*512 + t*2
    const int aw0 = arow_l * 128 + (((q * 2 + 0) ^ (arow_l & 7)) << 4);
    const int aw1 = arow_l * 128 + (((q * 2 + 1) ^ (arow_l & 7)) << 4);
    const int bw = 8192 + t * 32;

    f32x4 acc[8];
#pragma unroll
    for (int i = 0; i < 8; i++) acc[i] = (f32x4)0.f;

    // prologue: loads for s=0,1; write s=0 into slot0
    float4 cA0 = ap[q * 2], cA1 = ap[q * 2 + 1];
    float4 cB0 = bp[t * 2], cB1 = bp[t * 2 + 1];
    float4 nA0 = ap[8 + q * 2], nA1 = ap[8 + q * 2 + 1];
    float4 nB0 = bp[512 + t * 2], nB1 = bp[512 + t * 2 + 1];
    wr_stage(lds[0], aw0, aw1, bw, cA0, cA1, cB0, cB1);
    asm volatile("s_waitcnt lgkmcnt(0)" ::: "memory");
    __builtin_amdgcn_s_barrier();
    __builtin_amdgcn_sched_barrier(0);

#pragma unroll 2
    for (int s = 0; s < 62; s++) {
        // issue loads for stage s+2 (stay in flight across compute+write)
        float4 fA0 = ap[(s + 2) * 8 + q * 2], fA1 = ap[(s + 2) * 8 + q * 2 + 1];
        float4 fB0 = bp[(s + 2) * 512 + t * 2], fB1 = bp[(s + 2) * 512 + t * 2 + 1];

        compute_step(lds[s & 1], lane, wave, acc);
        __builtin_amdgcn_s_barrier();                 // all waves done reading slot s&1
        __builtin_amdgcn_sched_barrier(0);

        wr_stage(lds[(s + 1) & 1], aw0, aw1, bw, nA0, nA1, nB0, nB1);
        asm volatile("s_waitcnt lgkmcnt(0)" ::: "memory");
        __builtin_amdgcn_s_barrier();                 // slot (s+1)&1 now readable
        __builtin_amdgcn_sched_barrier(0);

        nA0 = fA0; nA1 = fA1; nB0 = fB0; nB1 = fB1;
    }
    // peeled tail: s=62 (write s=63), s=63 (compute only)
    compute_step(lds[0], lane, wave, acc);
    __builtin_amdgcn_s_barrier();
    __builtin_amdgcn_sched_barrier(0);
    wr_stage(lds[1], aw0, aw1, bw, nA0, nA1, nB0, nB1);
    asm volatile("s_waitcnt lgkmcnt(0)" ::: "memory");
    __builtin_amdgcn_s_barrier();
    __builtin_amdgcn_sched_barrier(0);
    compute_step(lds[1], lane, wave, acc);

    // ---- fused dual GEMM epilogue (wave-private hl, no barriers needed) ----
    u16* hl = hlbuf[wave];
#pragma unroll
    for (int nf = 0; nf < 8; nf++) {
        const int col = nf * 16 + lrow;
        const float bias = Bv[col];
#pragma unroll
        for (int r = 0; r < 4; r++) {
            const int row = lgrp * 4 + r;
            hl[row * 128 + (((col >> 3) ^ (row & 7)) << 3) + (col & 7)] =
                f2bf(lrelu(acc[nf][r] + bias));
        }
    }
    bf16x8 af2[4];
#pragma unroll
    for (int ks = 0; ks < 4; ks++)
        af2[ks] = *(const bf16x8*)(hl + lrow * 128 + ((((ks << 2) + lgrp) ^ (lrow & 7)) << 3));

    f32x4 dacc[8];
#pragma unroll
    for (int i = 0; i < 8; i++) dacc[i] = (f32x4)0.f;
    const u16* bp2 = Wf2 + lane * 8;
#pragma unroll
    for (int ks = 0; ks < 4; ks++) {
#pragma unroll
        for (int nf = 0; nf < 8; nf++) {
            bf16x8 bf = *(const bf16x8*)(bp2 + ks * 4096 + nf * 512);
            dacc[nf] = __builtin_amdgcn_mfma_f32_16x16x32_bf16(af2[ks], bf, dacc[nf], 0, 0, 0);
        }
    }

    const int rbase = m0 + wave * 16 + lgrp * 4;
#pragma unroll
    for (int nf = 0; nf < 8; nf++) {
        const int col = nf * 16 + lrow;
#pragma unroll
        for (int r = 0; r < 4; r++) {
            const int row = rbase + r;
            if (row < N_NODES) {
                if (col < 64) t1[(size_t)row * 64 + col] = f2bf(dacc[nf][r]);
                else          acc1[(size_t)row * 64 + (col - 64)] = dacc[nf][r] + brel[col - 64];
            }
        }
    }

    // ---- CSR fill tail (hidden in block-retirement tail) ----
    for (int e = blockIdx.x * 256 + t; e < N_EDGES; e += LIN_BLOCKS * 256) {
        const int dst = ei[N_EDGES + e];
        const int p = atomicAdd(cur + dst, 1);
        csr[p] = ei[e];
    }
}

// ---------------------------------------------------------------------------
// k_dualf2: t2(bf16)/acc2(f32) from lrelu(acc1)  (K=64, N=64)
// ---------------------------------------------------------------------------
__launch_bounds__(256, 2)
__global__ void k_dualf2(const float* __restrict__ A, const u16* __restrict__ Wf,
                         const float* __restrict__ brel,
                         u16* __restrict__ t2, float* __restrict__ acc2)
{
    const int t = threadIdx.x, wave = t >> 6, lane = t & 63;
    const int lrow = lane & 15, lgrp = lane >> 4;
    const int arow = blockIdx.x * 64 + wave * 16 + lrow;
    const float* ap = A + (size_t)(arow < N_NODES ? arow : 0) * 64 + 8 * lgrp;
    const u16* bp = Wf + lane * 8;

    float4 a00 = *(const float4*)(ap + 0);
    float4 a01 = *(const float4*)(ap + 4);
    float4 a10 = *(const float4*)(ap + 32);
    float4 a11 = *(const float4*)(ap + 36);

    f32x4 acc[4];
#pragma unroll
    for (int i = 0; i < 4; i++) acc[i] = (f32x4)0.f;

    a00.x = lrelu(a00.x); a00.y = lrelu(a00.y); a00.z = lrelu(a00.z); a00.w = lrelu(a00.w);
    a01.x = lrelu(a01.x); a01.y = lrelu(a01.y); a01.z = lrelu(a01.z); a01.w = lrelu(a01.w);
    bf16x8 af0 = cvt8(a00, a01);
    a10.x = lrelu(a10.x); a10.y = lrelu(a10.y); a10.z = lrelu(a10.z); a10.w = lrelu(a10.w);
    a11.x = lrelu(a11.x); a11.y = lrelu(a11.y); a11.z = lrelu(a11.z); a11.w = lrelu(a11.w);
    bf16x8 af1 = cvt8(a10, a11);

#pragma unroll
    for (int nf = 0; nf < 4; nf++) {
        bf16x8 b0 = *(const bf16x8*)(bp + nf * 512);
        bf16x8 b1 = *(const bf16x8*)(bp + 2048 + nf * 512);
        acc[nf] = __builtin_amdgcn_mfma_f32_16x16x32_bf16(af0, b0, acc[nf], 0, 0, 0);
        acc[nf] = __builtin_amdgcn_mfma_f32_16x16x32_bf16(af1, b1, acc[nf], 0, 0, 0);
    }

    const int rbase = blockIdx.x * 64 + wave * 16 + lgrp * 4;
#pragma unroll
    for (int nf = 0; nf < 4; nf++) {
        const int col = nf * 16 + lrow;
#pragma unroll
        for (int r = 0; r < 4; r++) {
            const int row = rbase + r;
            if (row < N_NODES) {
                if (col < 32) t2[(size_t)row * 32 + col] = f2bf(acc[nf][r]);
                else          acc2[(size_t)row * 32 + (col - 32)] = acc[nf][r] + brel[col - 32];
            }
        }
    }
}

// ---------------------------------------------------------------------------
// scans (CSR offsets)
// ---------------------------------------------------------------------------
__launch_bounds__(256)
__global__ void k_scan1(const int* __restrict__ deg, int* __restrict__ tmp,
                        int* __restrict__ bsum)
{
    __shared__ int sm[256];
    const int tid = threadIdx.x;
    const int i = blockIdx.x * 256 + tid;
    int d = (i < N_NODES) ? deg[i] : 0;
    sm[tid] = d;
    __syncthreads();
#pragma unroll
    for (int off = 1; off < 256; off <<= 1) {
        int v = (tid >= off) ? sm[tid - off] : 0;
        __syncthreads();
        sm[tid] += v;
        __syncthreads();
    }
    if (i < N_NODES) tmp[i] = sm[tid];
    if (tid == 255) bsum[blockIdx.x] = sm[255];
}

__launch_bounds__(256)
__global__ void k_scan2p(const int* __restrict__ bsum, int* __restrict__ boff, int nb)
{
    __shared__ int sm[256];
    const int tid = threadIdx.x;
    int v = (tid < nb) ? bsum[tid] : 0;
    sm[tid] = v;
    __syncthreads();
#pragma unroll
    for (int off = 1; off < 256; off <<= 1) {
        int u = (tid >= off) ? sm[tid - off] : 0;
        __syncthreads();
        sm[tid] += u;
        __syncthreads();
    }
    if (tid < nb) boff[tid] = sm[tid] - v;
}

__launch_bounds__(256)
__global__ void k_scan3(const int* __restrict__ tmp, const int* __restrict__ boff,
                        const int* __restrict__ deg, int* __restrict__ ro,
                        int* __restrict__ cur)
{
    const int i = blockIdx.x * 256 + threadIdx.x;
    if (i < N_NODES) {
        int incl = tmp[i] + boff[i >> 8];
        ro[i + 1] = incl;
        cur[i] = incl - deg[i];
    }
    if (i == 0) ro[0] = 0;
}

// ---------------------------------------------------------------------------
// k_gather64: acc1[n] += sum over in-edges of t1(bf16)[src]; wave/node
// ---------------------------------------------------------------------------
__launch_bounds__(256)
__global__ void k_gather64(const int* __restrict__ ro, const int* __restrict__ csr,
                           const u16* __restrict__ t, float* __restrict__ acc)
{
    const int wid = (blockIdx.x << 2) | (threadIdx.x >> 6);
    if (wid >= N_NODES) return;
    const int lane = threadIdx.x & 63;
    const int s = ro[wid], e = ro[wid + 1];
    float a = acc[(size_t)wid * 64 + lane];
    int i = s;
    for (; i + 8 <= e; i += 8) {
        int s0 = csr[i], s1 = csr[i + 1], s2 = csr[i + 2], s3 = csr[i + 3];
        int s4 = csr[i + 4], s5 = csr[i + 5], s6 = csr[i + 6], s7 = csr[i + 7];
        u16 v0 = t[(size_t)s0 * 64 + lane], v1 = t[(size_t)s1 * 64 + lane];
        u16 v2 = t[(size_t)s2 * 64 + lane], v3 = t[(size_t)s3 * 64 + lane];
        u16 v4 = t[(size_t)s4 * 64 + lane], v5 = t[(size_t)s5 * 64 + lane];
        u16 v6 = t[(size_t)s6 * 64 + lane], v7 = t[(size_t)s7 * 64 + lane];
        a += bf2f(v0); a += bf2f(v1); a += bf2f(v2); a += bf2f(v3);
        a += bf2f(v4); a += bf2f(v5); a += bf2f(v6); a += bf2f(v7);
    }
    for (; i < e; ++i) a += bf2f(t[(size_t)csr[i] * 64 + lane]);
    acc[(size_t)wid * 64 + lane] = a;
}

// ---------------------------------------------------------------------------
// k_gpos: fused gather32 + lrelu + pos GEMV
// ---------------------------------------------------------------------------
__launch_bounds__(256)
__global__ void k_gpos(const int* __restrict__ ro, const int* __restrict__ csr,
                       const u16* __restrict__ t, const float* __restrict__ acc2,
                       const float* __restrict__ PW, const float* __restrict__ PB,
                       float* __restrict__ out)
{
    const int wid = (blockIdx.x << 2) | (threadIdx.x >> 6);
    if (wid >= N_NODES) return;
    const int lane = threadIdx.x & 63;
    const int half = lane >> 5, f = lane & 31;
    const int s = ro[wid], e = ro[wid + 1];
    float a = 0.f;
    int i = s;
    for (; i + 8 <= e; i += 8) {
        int s0 = csr[i + half], s1 = csr[i + 2 + half];
        int s2 = csr[i + 4 + half], s3 = csr[i + 6 + half];
        u16 v0 = t[(size_t)s0 * 32 + f], v1 = t[(size_t)s1 * 32 + f];
        u16 v2 = t[(size_t)s2 * 32 + f], v3 = t[(size_t)s3 * 32 + f];
        a += bf2f(v0); a += bf2f(v1); a += bf2f(v2); a += bf2f(v3);
    }
    for (; i < e; i += 2) {
        int idx = i + half;
        if (idx < e) a += bf2f(t[(size_t)csr[idx] * 32 + f]);
    }
    a += __shfl_xor(a, 32, 64);

    float v = lrelu(acc2[(size_t)wid * 32 + f] + a);
    float p0 = v * PW[f], p1 = v * PW[32 + f], p2 = v * PW[64 + f];
#pragma unroll
    for (int off = 16; off >= 1; off >>= 1) {
        p0 += __shfl_xor(p0, off, 64);
        p1 += __shfl_xor(p1, off, 64);
        p2 += __shfl_xor(p2, off, 64);
    }
    if (lane == 0) {
        out[(size_t)wid * 3 + 0] = p0 + PB[0];
        out[(size_t)wid * 3 + 1] = p1 + PB[1];
        out[(size_t)wid * 3 + 2] = p2 + PB[2];
    }
}

// ---------------------------------------------------------------------------
extern "C" void kernel_launch(void* const* d_in, const int* in_sizes, int n_in,
                              void* d_out, int out_size, void* d_ws, size_t ws_size,
                              hipStream_t stream)
{
    const float* x        = (const float*)d_in[0];
    const int*   ei       = (const int*)d_in[1];
    const float* lin1_w   = (const float*)d_in[2];
    const float* lin1_b   = (const float*)d_in[3];
    const float* c1_wrel  = (const float*)d_in[4];
    const float* c1_brel  = (const float*)d_in[5];
    const float* c1_wroot = (const float*)d_in[6];
    const float* c4_wrel  = (const float*)d_in[7];
    const float* c4_brel  = (const float*)d_in[8];
    const float* c4_wroot = (const float*)d_in[9];
    const float* pos_w    = (const float*)d_in[10];
    const float* pos_b    = (const float*)d_in[11];
    float* out = (float*)d_out;

    char* base = (char*)d_ws;
    u16*   t1b  = (u16*)base;                        // [N][64] bf16 = 6.4 MB
    float* acc1 = (float*)(base + 6400000);          // [N][64] f32  = 12.8 MB
    u16*   t2b  = (u16*)(base + 19200000);           // [N][32] bf16 = 3.2 MB
    float* acc2 = (float*)(base + 22400000);         // [N][32] f32  = 6.4 MB
    u16*   wf1  = (u16*)(base + 28800000);           // 512 KB
    u16*   wf2  = wf1 + 262144;                      // 32 KB
    u16*   wf3  = wf2 + 16384;                       // 8 KB
    int*   ibase = (int*)(wf3 + 4096);
    const int NPAD = ((N_NODES + 255) / 256) * 256;  // 50176
    int* deg  = ibase;
    int* tmp  = deg  + NPAD;
    int* ro   = tmp  + NPAD;
    int* cur  = ro   + NPAD;
    int* bsum = cur  + NPAD;
    int* boff = bsum + 256;
    int* csr  = boff + 256;
    const int NB = (N_NODES + 255) / 256;            // 196

    // deg = 0 (async memset is graph-capturable), then tables + hist together
    hipMemsetAsync(deg, 0, (size_t)NPAD * sizeof(int), stream);
    hipLaunchKernelGGL(k_prep, dim3(1104 + HIST_BLOCKS), dim3(256), 0, stream,
                       lin1_w, c1_wrel, c1_wroot, c4_wrel, c4_wroot,
                       wf1, wf2, wf3, ei, deg);
    hipLaunchKernelGGL(k_scan1, dim3(NB), dim3(256), 0, stream, deg, tmp, bsum);
    hipLaunchKernelGGL(k_scan2p, dim3(1), dim3(256), 0, stream, bsum, boff, NB);
    hipLaunchKernelGGL(k_scan3, dim3(NB), dim3(256), 0, stream, tmp, boff, deg, ro, cur);

    // fused: h1(in-LDS) -> t1/acc1 ; + CSR fill tail
    hipLaunchKernelGGL(k_linf, dim3(LIN_BLOCKS), dim3(256), 0, stream,
                       x, wf1, wf2, lin1_b, c1_brel, t1b, acc1, ei, cur, csr);
    // acc1 += gather(t1)
    hipLaunchKernelGGL(k_gather64, dim3((N_NODES + 3) / 4), dim3(256), 0, stream,
                       ro, csr, t1b, acc1);
    // t2/acc2
    hipLaunchKernelGGL(k_dualf2, dim3((N_NODES + 63) / 64), dim3(256), 0, stream,
                       acc1, wf3, c4_brel, t2b, acc2);
    // out = lrelu(acc2 + gather(t2)) @ pos_w.T + pos_b
    hipLaunchKernelGGL(k_gpos, dim3((N_NODES + 3) / 4), dim3(256), 0, stream,
                       ro, csr, t2b, acc2, pos_w, pos_b, out);
}

// Round 9
// 361.408 us; speedup vs baseline: 1.3025x; 1.0228x over previous
//
#include <hip/hip_runtime.h>

#define N_NODES 50000
#define N_EDGES 1600000
#define LIN_BLOCKS 782
#define HIST_BLOCKS 1024

typedef __attribute__((ext_vector_type(4))) float f32x4;
typedef __attribute__((ext_vector_type(8))) short bf16x8;
typedef unsigned short u16;

__device__ __forceinline__ float lrelu(float x) { return x >= 0.f ? x : 0.01f * x; }

__device__ __forceinline__ u16 f2bf(float f) {
    union { float f; unsigned u; } v; v.f = f;
    unsigned u = v.u;
    u += 0x7fffu + ((u >> 16) & 1u);
    return (u16)(u >> 16);
}

__device__ __forceinline__ float bf2f(u16 v) {
    union { unsigned u; float f; } x; x.u = ((unsigned)v) << 16; return x.f;
}

__device__ __forceinline__ bf16x8 cvt8(float4 a, float4 b) {
    bf16x8 r;
    r[0] = (short)f2bf(a.x); r[1] = (short)f2bf(a.y);
    r[2] = (short)f2bf(a.z); r[3] = (short)f2bf(a.w);
    r[4] = (short)f2bf(b.x); r[5] = (short)f2bf(b.y);
    r[6] = (short)f2bf(b.z); r[7] = (short)f2bf(b.w);
    return r;
}

// ---------------------------------------------------------------------------
// k_prep: fragment-ordered bf16 weight tables + hist (deg pre-zeroed by
// hipMemsetAsync). Wf layout [kstep][nf][lane][8].
// ---------------------------------------------------------------------------
__launch_bounds__(256)
__global__ void k_prep(const float* __restrict__ W1,
                       const float* __restrict__ W2a, const float* __restrict__ W2b,
                       const float* __restrict__ W3a, const float* __restrict__ W3b,
                       u16* __restrict__ wf1, u16* __restrict__ wf2, u16* __restrict__ wf3,
                       const int* __restrict__ ei, int* __restrict__ deg)
{
    const int b = blockIdx.x;
    if (b < 1024) {
        int i = b * 256 + threadIdx.x;
        int e = i & 7, lane = (i >> 3) & 63, nf = (i >> 9) & 7, ks = i >> 12;
        int n = nf * 16 + (lane & 15);
        int k = ks * 32 + 8 * (lane >> 4) + e;
        wf1[i] = f2bf(W1[(size_t)n * 2048 + k]);
    } else if (b < 1088) {
        int i = (b - 1024) * 256 + threadIdx.x;
        int e = i & 7, lane = (i >> 3) & 63, nf = (i >> 9) & 7, ks = i >> 12;
        int n = nf * 16 + (lane & 15);
        int k = ks * 32 + 8 * (lane >> 4) + e;
        float v = (n < 64) ? W2a[(size_t)n * 128 + k] : W2b[(size_t)(n - 64) * 128 + k];
        wf2[i] = f2bf(v);
    } else if (b < 1104) {
        int i = (b - 1088) * 256 + threadIdx.x;
        int e = i & 7, lane = (i >> 3) & 63, nf = (i >> 9) & 3, ks = i >> 11;
        int n = nf * 16 + (lane & 15);
        int k = ks * 32 + 8 * (lane >> 4) + e;
        float v = (n < 32) ? W3a[(size_t)n * 64 + k] : W3b[(size_t)(n - 32) * 64 + k];
        wf3[i] = f2bf(v);
    } else {
        for (int e = (b - 1104) * 256 + threadIdx.x; e < N_EDGES; e += HIST_BLOCKS * 256)
            atomicAdd(deg + ei[N_EDGES + e], 1);
    }
}

// ---------------------------------------------------------------------------
// k_linf: FUSED  h1 = lrelu(x @ lin1_w.T + b) -> t1/acc1 ; + CSR-fill tail.
// Reg-staged 2-slot ping-pong, 2-stage lookahead, raw s_barrier + lgkmcnt
// (global loads stay in flight across barriers).
// Slot (12 KB) = A[64r][32k bf16, k16^(row&3) swizzle] 4KB + B[8KB wf1 slice].
// Wave layout 2x2: wave = 32 rows x 64 cols (2 strips x 4 nf) -> B LDS reads
// halved. 24KB LDS + launch_bounds(256,4) -> 4 blocks/CU -> all 782 resident.
// ---------------------------------------------------------------------------
__device__ __forceinline__ void compute_step(const char* slot, int lane, int wave,
                                             f32x4 acc[2][4])
{
    const int lrow = lane & 15;
    const int k16 = lane >> 4;
    const int nfb = (wave >> 1) << 2;            // nf base (0 or 4)
    const int rb = (wave & 1) << 5;              // row base (0 or 32)

    bf16x8 af[2];
#pragma unroll
    for (int st = 0; st < 2; st++) {
        const int row = rb + st * 16 + lrow;
        af[st] = *(const bf16x8*)(slot + row * 64 + ((k16 ^ (row & 3)) << 4));
    }
    bf16x8 bf[4];
#pragma unroll
    for (int j = 0; j < 4; j++)
        bf[j] = *(const bf16x8*)(slot + 4096 + (nfb + j) * 1024 + lane * 16);

    __builtin_amdgcn_s_setprio(1);
#pragma unroll
    for (int st = 0; st < 2; st++)
#pragma unroll
        for (int j = 0; j < 4; j++)
            acc[st][j] = __builtin_amdgcn_mfma_f32_16x16x32_bf16(af[st], bf[j], acc[st][j], 0, 0, 0);
    __builtin_amdgcn_s_setprio(0);
}

__launch_bounds__(256, 4)
__global__ void k_linf(const float* __restrict__ X, const u16* __restrict__ Wf1,
                       const u16* __restrict__ Wf2,
                       const float* __restrict__ Bv, const float* __restrict__ brel,
                       u16* __restrict__ t1, float* __restrict__ acc1,
                       const int* __restrict__ ei, int* __restrict__ cur,
                       int* __restrict__ csr)
{
    __shared__ __align__(16) char lds[2][12288];

    const int t = threadIdx.x, wave = t >> 6, lane = t & 63;
    const int lrow = lane & 15, lgrp = lane >> 4;
    const int m0 = blockIdx.x * 64;

    // staging geometry: thread t stages row=t>>2, k-chunk kq=t&3 (8 elems)
    const int arow_l = t >> 2, kq = t & 3;
    int grow = m0 + arow_l; if (grow >= N_NODES) grow = N_NODES - 1;
    const float4* ap = (const float4*)(X + (size_t)grow * 2048);   // + s*8 + kq*2
    const bf16x8* bp = (const bf16x8*)Wf1;                          // + s*512 + t*2
    const int awr = arow_l * 64 + ((kq ^ (arow_l & 3)) << 4);
    const int bwr = 4096 + t * 32;

    f32x4 acc[2][4];
#pragma unroll
    for (int st = 0; st < 2; st++)
#pragma unroll
        for (int j = 0; j < 4; j++) acc[st][j] = (f32x4)0.f;

    // prologue: s=0 (c), s=1 (n); write s=0 into slot0
    float4 cA0 = ap[kq * 2], cA1 = ap[kq * 2 + 1];
    bf16x8 cB0 = bp[t * 2], cB1 = bp[t * 2 + 1];
    float4 nA0 = ap[8 + kq * 2], nA1 = ap[8 + kq * 2 + 1];
    bf16x8 nB0 = bp[512 + t * 2], nB1 = bp[512 + t * 2 + 1];
    *(bf16x8*)(lds[0] + awr) = cvt8(cA0, cA1);
    *(bf16x8*)(lds[0] + bwr) = cB0;
    *(bf16x8*)(lds[0] + bwr + 16) = cB1;
    asm volatile("s_waitcnt lgkmcnt(0)" ::: "memory");
    __builtin_amdgcn_s_barrier();
    __builtin_amdgcn_sched_barrier(0);

#pragma unroll 2
    for (int s = 0; s < 62; s++) {
        // issue loads for stage s+2
        float4 fA0 = ap[(s + 2) * 8 + kq * 2], fA1 = ap[(s + 2) * 8 + kq * 2 + 1];
        bf16x8 fB0 = bp[(s + 2) * 512 + t * 2], fB1 = bp[(s + 2) * 512 + t * 2 + 1];

        compute_step(lds[s & 1], lane, wave, acc);
        __builtin_amdgcn_s_barrier();                 // all waves done reading slot s&1
        __builtin_amdgcn_sched_barrier(0);

        char* wslot = lds[(s + 1) & 1];
        *(bf16x8*)(wslot + awr) = cvt8(nA0, nA1);
        *(bf16x8*)(wslot + bwr) = nB0;
        *(bf16x8*)(wslot + bwr + 16) = nB1;
        asm volatile("s_waitcnt lgkmcnt(0)" ::: "memory");
        __builtin_amdgcn_s_barrier();                 // slot (s+1)&1 now readable
        __builtin_amdgcn_sched_barrier(0);

        nA0 = fA0; nA1 = fA1; nB0 = fB0; nB1 = fB1;
    }
    // peeled tail: s=62 (write s=63), s=63
    compute_step(lds[0], lane, wave, acc);
    __builtin_amdgcn_s_barrier();
    __builtin_amdgcn_sched_barrier(0);
    *(bf16x8*)(lds[1] + awr) = cvt8(nA0, nA1);
    *(bf16x8*)(lds[1] + bwr) = nB0;
    *(bf16x8*)(lds[1] + bwr + 16) = nB1;
    asm volatile("s_waitcnt lgkmcnt(0)" ::: "memory");
    __builtin_amdgcn_s_barrier();
    __builtin_amdgcn_sched_barrier(0);
    compute_step(lds[1], lane, wave, acc);
    __builtin_amdgcn_s_barrier();     // slot1 dead after this; hl overlays lds
    __builtin_amdgcn_sched_barrier(0);

    // ---- fused dual GEMM epilogue ----
    // shared hl[64][128] bf16 (16 KB overlaying slots), chunk-XOR swizzle:
    // h[row][col] -> u16 idx row*128 + ((col>>3)^(row&7))*8 + (col&7)
    u16* hl = (u16*)&lds[0][0];
    {
        const int nfb = (wave >> 1) << 2, rb = (wave & 1) << 5;
#pragma unroll
        for (int st = 0; st < 2; st++) {
#pragma unroll
            for (int j = 0; j < 4; j++) {
                const int col = nfb * 16 + j * 16 + lrow;
                const float bias = Bv[col];
#pragma unroll
                for (int r = 0; r < 4; r++) {
                    const int row = rb + st * 16 + lgrp * 4 + r;
                    hl[row * 128 + (((col >> 3) ^ (row & 7)) << 3) + (col & 7)] =
                        f2bf(lrelu(acc[st][j][r] + bias));
                }
            }
        }
    }
    asm volatile("s_waitcnt lgkmcnt(0)" ::: "memory");
    __builtin_amdgcn_s_barrier();
    __builtin_amdgcn_sched_barrier(0);

    // dual GEMM: wave handles rows wave*16..+16, all 8 nf (K=128)
    bf16x8 af2[4];
    {
        const int row = wave * 16 + lrow;
#pragma unroll
        for (int ks = 0; ks < 4; ks++) {
            const int chunk = ((ks << 2) + lgrp) ^ (row & 7);
            af2[ks] = *(const bf16x8*)(hl + row * 128 + (chunk << 3));
        }
    }
    f32x4 dacc[8];
#pragma unroll
    for (int i = 0; i < 8; i++) dacc[i] = (f32x4)0.f;
    const u16* bp2 = Wf2 + lane * 8;
#pragma unroll
    for (int ks = 0; ks < 4; ks++) {
#pragma unroll
        for (int nf = 0; nf < 8; nf++) {
            bf16x8 bf = *(const bf16x8*)(bp2 + ks * 4096 + nf * 512);
            dacc[nf] = __builtin_amdgcn_mfma_f32_16x16x32_bf16(af2[ks], bf, dacc[nf], 0, 0, 0);
        }
    }

    const int rbase = m0 + wave * 16 + lgrp * 4;
#pragma unroll
    for (int nf = 0; nf < 8; nf++) {
        const int col = nf * 16 + lrow;
#pragma unroll
        for (int r = 0; r < 4; r++) {
            const int row = rbase + r;
            if (row < N_NODES) {
                if (col < 64) t1[(size_t)row * 64 + col] = f2bf(dacc[nf][r]);
                else          acc1[(size_t)row * 64 + (col - 64)] = dacc[nf][r] + brel[col - 64];
            }
        }
    }

    // ---- CSR fill tail ----
    for (int e = blockIdx.x * 256 + t; e < N_EDGES; e += LIN_BLOCKS * 256) {
        const int dst = ei[N_EDGES + e];
        const int p = atomicAdd(cur + dst, 1);
        csr[p] = ei[e];
    }
}

// ---------------------------------------------------------------------------
// k_dualf2: t2(bf16)/acc2(f32) from lrelu(acc1)  (K=64, N=64)
// ---------------------------------------------------------------------------
__launch_bounds__(256, 2)
__global__ void k_dualf2(const float* __restrict__ A, const u16* __restrict__ Wf,
                         const float* __restrict__ brel,
                         u16* __restrict__ t2, float* __restrict__ acc2)
{
    const int t = threadIdx.x, wave = t >> 6, lane = t & 63;
    const int lrow = lane & 15, lgrp = lane >> 4;
    const int arow = blockIdx.x * 64 + wave * 16 + lrow;
    const float* ap = A + (size_t)(arow < N_NODES ? arow : 0) * 64 + 8 * lgrp;
    const u16* bp = Wf + lane * 8;

    float4 a00 = *(const float4*)(ap + 0);
    float4 a01 = *(const float4*)(ap + 4);
    float4 a10 = *(const float4*)(ap + 32);
    float4 a11 = *(const float4*)(ap + 36);

    f32x4 acc[4];
#pragma unroll
    for (int i = 0; i < 4; i++) acc[i] = (f32x4)0.f;

    a00.x = lrelu(a00.x); a00.y = lrelu(a00.y); a00.z = lrelu(a00.z); a00.w = lrelu(a00.w);
    a01.x = lrelu(a01.x); a01.y = lrelu(a01.y); a01.z = lrelu(a01.z); a01.w = lrelu(a01.w);
    bf16x8 af0 = cvt8(a00, a01);
    a10.x = lrelu(a10.x); a10.y = lrelu(a10.y); a10.z = lrelu(a10.z); a10.w = lrelu(a10.w);
    a11.x = lrelu(a11.x); a11.y = lrelu(a11.y); a11.z = lrelu(a11.z); a11.w = lrelu(a11.w);
    bf16x8 af1 = cvt8(a10, a11);

#pragma unroll
    for (int nf = 0; nf < 4; nf++) {
        bf16x8 b0 = *(const bf16x8*)(bp + nf * 512);
        bf16x8 b1 = *(const bf16x8*)(bp + 2048 + nf * 512);
        acc[nf] = __builtin_amdgcn_mfma_f32_16x16x32_bf16(af0, b0, acc[nf], 0, 0, 0);
        acc[nf] = __builtin_amdgcn_mfma_f32_16x16x32_bf16(af1, b1, acc[nf], 0, 0, 0);
    }

    const int rbase = blockIdx.x * 64 + wave * 16 + lgrp * 4;
#pragma unroll
    for (int nf = 0; nf < 4; nf++) {
        const int col = nf * 16 + lrow;
#pragma unroll
        for (int r = 0; r < 4; r++) {
            const int row = rbase + r;
            if (row < N_NODES) {
                if (col < 32) t2[(size_t)row * 32 + col] = f2bf(acc[nf][r]);
                else          acc2[(size_t)row * 32 + (col - 32)] = acc[nf][r] + brel[col - 32];
            }
        }
    }
}

// ---------------------------------------------------------------------------
// scans (CSR offsets)
// ---------------------------------------------------------------------------
__launch_bounds__(256)
__global__ void k_scan1(const int* __restrict__ deg, int* __restrict__ tmp,
                        int* __restrict__ bsum)
{
    __shared__ int sm[256];
    const int tid = threadIdx.x;
    const int i = blockIdx.x * 256 + tid;
    int d = (i < N_NODES) ? deg[i] : 0;
    sm[tid] = d;
    __syncthreads();
#pragma unroll
    for (int off = 1; off < 256; off <<= 1) {
        int v = (tid >= off) ? sm[tid - off] : 0;
        __syncthreads();
        sm[tid] += v;
        __syncthreads();
    }
    if (i < N_NODES) tmp[i] = sm[tid];
    if (tid == 255) bsum[blockIdx.x] = sm[255];
}

__launch_bounds__(256)
__global__ void k_scan2p(const int* __restrict__ bsum, int* __restrict__ boff, int nb)
{
    __shared__ int sm[256];
    const int tid = threadIdx.x;
    int v = (tid < nb) ? bsum[tid] : 0;
    sm[tid] = v;
    __syncthreads();
#pragma unroll
    for (int off = 1; off < 256; off <<= 1) {
        int u = (tid >= off) ? sm[tid - off] : 0;
        __syncthreads();
        sm[tid] += u;
        __syncthreads();
    }
    if (tid < nb) boff[tid] = sm[tid] - v;
}

__launch_bounds__(256)
__global__ void k_scan3(const int* __restrict__ tmp, const int* __restrict__ boff,
                        const int* __restrict__ deg, int* __restrict__ ro,
                        int* __restrict__ cur)
{
    const int i = blockIdx.x * 256 + threadIdx.x;
    if (i < N_NODES) {
        int incl = tmp[i] + boff[i >> 8];
        ro[i + 1] = incl;
        cur[i] = incl - deg[i];
    }
    if (i == 0) ro[0] = 0;
}

// ---------------------------------------------------------------------------
// k_gather64: acc1[n] += sum over in-edges of t1(bf16)[src]; wave/node
// ---------------------------------------------------------------------------
__launch_bounds__(256)
__global__ void k_gather64(const int* __restrict__ ro, const int* __restrict__ csr,
                           const u16* __restrict__ t, float* __restrict__ acc)
{
    const int wid = (blockIdx.x << 2) | (threadIdx.x >> 6);
    if (wid >= N_NODES) return;
    const int lane = threadIdx.x & 63;
    const int s = ro[wid], e = ro[wid + 1];
    float a = acc[(size_t)wid * 64 + lane];
    int i = s;
    for (; i + 8 <= e; i += 8) {
        int s0 = csr[i], s1 = csr[i + 1], s2 = csr[i + 2], s3 = csr[i + 3];
        int s4 = csr[i + 4], s5 = csr[i + 5], s6 = csr[i + 6], s7 = csr[i + 7];
        u16 v0 = t[(size_t)s0 * 64 + lane], v1 = t[(size_t)s1 * 64 + lane];
        u16 v2 = t[(size_t)s2 * 64 + lane], v3 = t[(size_t)s3 * 64 + lane];
        u16 v4 = t[(size_t)s4 * 64 + lane], v5 = t[(size_t)s5 * 64 + lane];
        u16 v6 = t[(size_t)s6 * 64 + lane], v7 = t[(size_t)s7 * 64 + lane];
        a += bf2f(v0); a += bf2f(v1); a += bf2f(v2); a += bf2f(v3);
        a += bf2f(v4); a += bf2f(v5); a += bf2f(v6); a += bf2f(v7);
    }
    for (; i < e; ++i) a += bf2f(t[(size_t)csr[i] * 64 + lane]);
    acc[(size_t)wid * 64 + lane] = a;
}

// ---------------------------------------------------------------------------
// k_gpos: fused gather32 + lrelu + pos GEMV
// ---------------------------------------------------------------------------
__launch_bounds__(256)
__global__ void k_gpos(const int* __restrict__ ro, const int* __restrict__ csr,
                       const u16* __restrict__ t, const float* __restrict__ acc2,
                       const float* __restrict__ PW, const float* __restrict__ PB,
                       float* __restrict__ out)
{
    const int wid = (blockIdx.x << 2) | (threadIdx.x >> 6);
    if (wid >= N_NODES) return;
    const int lane = threadIdx.x & 63;
    const int half = lane >> 5, f = lane & 31;
    const int s = ro[wid], e = ro[wid + 1];
    float a = 0.f;
    int i = s;
    for (; i + 8 <= e; i += 8) {
        int s0 = csr[i + half], s1 = csr[i + 2 + half];
        int s2 = csr[i + 4 + half], s3 = csr[i + 6 + half];
        u16 v0 = t[(size_t)s0 * 32 + f], v1 = t[(size_t)s1 * 32 + f];
        u16 v2 = t[(size_t)s2 * 32 + f], v3 = t[(size_t)s3 * 32 + f];
        a += bf2f(v0); a += bf2f(v1); a += bf2f(v2); a += bf2f(v3);
    }
    for (; i < e; i += 2) {
        int idx = i + half;
        if (idx < e) a += bf2f(t[(size_t)csr[idx] * 32 + f]);
    }
    a += __shfl_xor(a, 32, 64);

    float v = lrelu(acc2[(size_t)wid * 32 + f] + a);
    float p0 = v * PW[f], p1 = v * PW[32 + f], p2 = v * PW[64 + f];
#pragma unroll
    for (int off = 16; off >= 1; off >>= 1) {
        p0 += __shfl_xor(p0, off, 64);
        p1 += __shfl_xor(p1, off, 64);
        p2 += __shfl_xor(p2, off, 64);
    }
    if (lane == 0) {
        out[(size_t)wid * 3 + 0] = p0 + PB[0];
        out[(size_t)wid * 3 + 1] = p1 + PB[1];
        out[(size_t)wid * 3 + 2] = p2 + PB[2];
    }
}

// ---------------------------------------------------------------------------
extern "C" void kernel_launch(void* const* d_in, const int* in_sizes, int n_in,
                              void* d_out, int out_size, void* d_ws, size_t ws_size,
                              hipStream_t stream)
{
    const float* x        = (const float*)d_in[0];
    const int*   ei       = (const int*)d_in[1];
    const float* lin1_w   = (const float*)d_in[2];
    const float* lin1_b   = (const float*)d_in[3];
    const float* c1_wrel  = (const float*)d_in[4];
    const float* c1_brel  = (const float*)d_in[5];
    const float* c1_wroot = (const float*)d_in[6];
    const float* c4_wrel  = (const float*)d_in[7];
    const float* c4_brel  = (const float*)d_in[8];
    const float* c4_wroot = (const float*)d_in[9];
    const float* pos_w    = (const float*)d_in[10];
    const float* pos_b    = (const float*)d_in[11];
    float* out = (float*)d_out;

    char* base = (char*)d_ws;
    u16*   t1b  = (u16*)base;                        // [N][64] bf16 = 6.4 MB
    float* acc1 = (float*)(base + 6400000);          // [N][64] f32  = 12.8 MB
    u16*   t2b  = (u16*)(base + 19200000);           // [N][32] bf16 = 3.2 MB
    float* acc2 = (float*)(base + 22400000);         // [N][32] f32  = 6.4 MB
    u16*   wf1  = (u16*)(base + 28800000);           // 512 KB
    u16*   wf2  = wf1 + 262144;                      // 32 KB
    u16*   wf3  = wf2 + 16384;                       // 8 KB
    int*   ibase = (int*)(wf3 + 4096);
    const int NPAD = ((N_NODES + 255) / 256) * 256;  // 50176
    int* deg  = ibase;
    int* tmp  = deg  + NPAD;
    int* ro   = tmp  + NPAD;
    int* cur  = ro   + NPAD;
    int* bsum = cur  + NPAD;
    int* boff = bsum + 256;
    int* csr  = boff + 256;
    const int NB = (N_NODES + 255) / 256;            // 196

    hipMemsetAsync(deg, 0, (size_t)NPAD * sizeof(int), stream);
    hipLaunchKernelGGL(k_prep, dim3(1104 + HIST_BLOCKS), dim3(256), 0, stream,
                       lin1_w, c1_wrel, c1_wroot, c4_wrel, c4_wroot,
                       wf1, wf2, wf3, ei, deg);
    hipLaunchKernelGGL(k_scan1, dim3(NB), dim3(256), 0, stream, deg, tmp, bsum);
    hipLaunchKernelGGL(k_scan2p, dim3(1), dim3(256), 0, stream, bsum, boff, NB);
    hipLaunchKernelGGL(k_scan3, dim3(NB), dim3(256), 0, stream, tmp, boff, deg, ro, cur);

    // fused: h1(in-LDS) -> t1/acc1 ; + CSR fill tail
    hipLaunchKernelGGL(k_linf, dim3(LIN_BLOCKS), dim3(256), 0, stream,
                       x, wf1, wf2, lin1_b, c1_brel, t1b, acc1, ei, cur, csr);
    // acc1 += gather(t1)
    hipLaunchKernelGGL(k_gather64, dim3((N_NODES + 3) / 4), dim3(256), 0, stream,
                       ro, csr, t1b, acc1);
    // t2/acc2
    hipLaunchKernelGGL(k_dualf2, dim3((N_NODES + 63) / 64), dim3(256), 0, stream,
                       acc1, wf3, c4_brel, t2b, acc2);
    // out = lrelu(acc2 + gather(t2)) @ pos_w.T + pos_b
    hipLaunchKernelGGL(k_gpos, dim3((N_NODES + 3) / 4), dim3(256), 0, stream,
                       ro, csr, t2b, acc2, pos_w, pos_b, out);
}